// Round 10
// baseline (147.258 us; speedup 1.0000x reference)
//
#include <hip/hip_runtime.h>
#include <stdint.h>

#define NPTS 16384

typedef __attribute__((ext_vector_type(8)))  __bf16   bf16x8;
typedef __attribute__((ext_vector_type(16))) float    f32x16;
typedef __attribute__((ext_vector_type(4)))  float    f32x4;
typedef __attribute__((ext_vector_type(4)))  uint32_t u32x4;

struct PrepArgs {
    const float* W[7];
    u32x4* dst;
    const float* l1; const float* l2;
    int run_on_zero;   // 1: run iff lambda==0; 0: run iff lambda!=0
};

struct Args {
    const float* W0; const float* b0;
    const float* bias[8];   // [1..7] valid
    const float* W8; const float* b8;
    const float* xs; const float* ys; const float* ts;
    const float* l1; const float* l2;
    const u32x4* wpk;       // packed W frags, 32x32 format (fallback)
    const u32x4* wpk16;     // packed W frags, 16x16 format (reduced path)
    float* out;
};

// ---------- bf16 helpers (verified) ----------
__device__ __forceinline__ uint32_t b16rne(float x) {
    uint32_t u = __float_as_uint(x);
    return (u + 0x7FFFu + ((u >> 16) & 1u)) >> 16;
}
__device__ __forceinline__ float fromb16(uint32_t h) { return __uint_as_float(h << 16); }

__device__ __forceinline__ void packPair(float a, float b, uint32_t& hw, uint32_t& lw) {
    uint32_t ha = b16rne(a), hb = b16rne(b);
    float la = a - fromb16(ha), lb = b - fromb16(hb);
    hw = ha | (hb << 16);
    lw = b16rne(la) | (b16rne(lb) << 16);
}

// packed RNE bf16 pair: low16 = bf16(a), high16 = bf16(b)
__device__ __forceinline__ uint32_t cvtpk_bf16(float a, float b) {
    uint32_t r;
    asm("v_cvt_pk_bf16_f32 %0, %1, %2" : "=v"(r) : "v"(a), "v"(b));
    return r;
}

__device__ __forceinline__ f32x16 mfma32(bf16x8 a, bf16x8 b, f32x16 c) {
    return __builtin_amdgcn_mfma_f32_32x32x16_bf16(a, b, c, 0, 0, 0);
}
__device__ __forceinline__ f32x4 mfma16(bf16x8 a, bf16x8 b, f32x4 c) {
    return __builtin_amdgcn_mfma_f32_16x16x32_bf16(a, b, c, 0, 0, 0);
}

__device__ __forceinline__ float fast_tanh(float x) {
    float e = __expf(2.0f * x);
    return 1.0f - __fdividef(2.0f, e + 1.0f);   // inf-safe
}

// ---------- full 13-channel tanh jet (verified, fallback path) ----------
__device__ __forceinline__ void tanh_jet(float u[13]) {
    float s    = fast_tanh(u[0]);
    float sp   = 1.f - s * s;
    float spp  = -2.f * s * sp;
    float sppp = -2.f * (sp * sp + s * spp);
    float u1 = u[1], u2 = u[2], u3 = u[3];
    float u4 = u[4], u5 = u[5], u6 = u[6];
    u[0] = s;
    u[1] = sp * u1;
    u[2] = sp * u2;
    u[3] = sp * u3;
    u[9]  = sppp * u1 * u1 * u1 + 3.f * spp * u1 * u4 + sp * u[9];
    u[10] = sppp * u1 * u1 * u2 + spp * (u4 * u2 + 2.f * u5 * u1) + sp * u[10];
    u[11] = sppp * u1 * u2 * u2 + spp * (u6 * u1 + 2.f * u5 * u2) + sp * u[11];
    u[12] = sppp * u2 * u2 * u2 + 3.f * spp * u2 * u6 + sp * u[12];
    u[4] = spp * u1 * u1 + sp * u4;
    u[5] = spp * u1 * u2 + sp * u5;
    u[6] = spp * u2 * u2 + sp * u6;
    u[7] = spp * u1 * u3 + sp * u[7];
    u[8] = spp * u2 * u3 + sp * u[8];
}

// ---------- reduced 6-channel jet: 0:val 1:dx 2:dy 3:dt 4:dxt 5:dyt ----------
__device__ __forceinline__ void tanh_jet6(float u[6]) {
    float s   = fast_tanh(u[0]);
    float sp  = 1.f - s * s;
    float spp = -2.f * s * sp;
    float u1 = u[1], u2 = u[2], u3 = u[3];
    u[0] = s;
    u[4] = spp * u1 * u3 + sp * u[4];
    u[5] = spp * u2 * u3 + sp * u[5];
    u[1] = sp * u1;
    u[2] = sp * u2;
    u[3] = sp * u3;
}

// ---------- prep A: 32x32 B-frag order (fallback format, verified) ----------
__global__ __launch_bounds__(256)
void pack_w_kernel(PrepArgs a) {
    bool z = (a.l1[0] == 0.f && a.l2[0] == 0.f);
    if (z == (bool)a.run_on_zero ? false : true) { /* see guard below */ }
    if (z != (bool)a.run_on_zero) return;
    int idx = blockIdx.x * 256 + threadIdx.x;   // 7*16*128 = 14336
    int L  = idx >> 11;
    int kb = (idx >> 7) & 15;
    int n  = idx & 127;
    const float* w = a.W[L] + n * 128 + kb * 8;
    float4 f0 = *(const float4*)w;
    float4 f1 = *(const float4*)(w + 4);
    uint32_t h0, h1, h2, h3, l0, l1, l2, l3;
    packPair(f0.x, f0.y, h0, l0);
    packPair(f0.z, f0.w, h1, l1);
    packPair(f1.x, f1.y, h2, l2);
    packPair(f1.z, f1.w, h3, l3);
    a.dst[((L * 2 + 0) * 16 + kb) * 128 + n] = u32x4{h0, h1, h2, h3};
    a.dst[((L * 2 + 1) * 16 + kb) * 128 + n] = u32x4{l0, l1, l2, l3};
}

// ---------- prep B: 16x16 B-frag order (reduced path) ----------
// B-frag for k-step s (k=32s..32s+31), lane-group g covers k = 32s+8g..+7:
// dst[((L*2+h)*16 + s*4+g)*128 + n] = u32x4 of bf16 pairs W[n][32s+8g+0..7]
__global__ __launch_bounds__(256)
void pack_w16_kernel(PrepArgs a) {
    bool z = (a.l1[0] == 0.f && a.l2[0] == 0.f);
    if (z != (bool)a.run_on_zero) return;
    int idx = blockIdx.x * 256 + threadIdx.x;   // 7*4*4*128 = 14336
    int L = idx >> 11;
    int s = (idx >> 9) & 3;
    int g = (idx >> 7) & 3;
    int n = idx & 127;
    const float* w = a.W[L] + n * 128 + s * 32 + g * 8;
    float4 f0 = *(const float4*)w;
    float4 f1 = *(const float4*)(w + 4);
    uint32_t h0, h1, h2, h3, l0, l1, l2, l3;
    packPair(f0.x, f0.y, h0, l0);
    packPair(f0.z, f0.w, h1, l1);
    packPair(f1.x, f1.y, h2, l2);
    packPair(f1.z, f1.w, h3, l3);
    a.dst[((L * 2 + 0) * 16 + s * 4 + g) * 128 + n] = u32x4{h0, h1, h2, h3};
    a.dst[((L * 2 + 1) * 16 + s * 4 + g) * 128 + n] = u32x4{l0, l1, l2, l3};
}

// ================= reduced path: lambda1 == lambda2 == 0 =================
// 8 points/block, M=48 rows = exactly 3 16-row MFMA tiles, zero pad.
// Row map: row(c,p) = 16*(c>>1) + 4*(p>>1) + (c&1) + 2*(p&1).
// 16x16x32 MFMA, C: col=lane&15, row=(lane>>4)*4+reg [m89-verified] =>
// lane (l15,g) holds, for neurons n0=wid*32+l15 and n0+16, the complete
// 6-channel jets of points p=2g+e at acc[ct][c>>1][(c&1)+2e] (static).
// A: two bf16 planes [48][128], 16B-granule XOR swizzle (verified):
//   addr(row,k) = row*128 + (((k>>3) ^ (row&15))<<3) + (k&7)
__global__ __launch_bounds__(256, 6)
void pinn_red8_kernel(Args args)
{
    if (args.l1[0] != 0.f || args.l2[0] != 0.f) return;   // uniform guard

    __shared__ ushort Ahi[48 * 128];        // 12 KB
    __shared__ ushort Alo[48 * 128];        // 12 KB
    __shared__ float  Part[4][4][2][9];     // 1.125 KB [wid][g][e][v]

    const int tid   = threadIdx.x;
    const int lane  = tid & 63;
    const int wid   = tid >> 6;
    const int l15   = lane & 15;
    const int g     = lane >> 4;            // 0..3
    const int n0    = wid * 32 + l15;       // ct=0 neuron; ct=1 -> +16
    const int pbase = blockIdx.x * 8;

    auto put_pair = [&](float dA, float dB, int rowA, int n) {
        const int rowB = rowA + 1;
        const int aA = rowA * 128 + ((((n >> 3) ^ (rowA & 15)) << 3) | (n & 7));
        const int aB = rowB * 128 + ((((n >> 3) ^ (rowB & 15)) << 3) | (n & 7));
        uint32_t hp = cvtpk_bf16(dA, dB);
        float hA = __uint_as_float(hp << 16);
        float hB = __uint_as_float(hp & 0xFFFF0000u);
        uint32_t lp = cvtpk_bf16(dA - hA, dB - hB);
        Ahi[aA] = (ushort)hp;  Ahi[aB] = (ushort)(hp >> 16);
        Alo[aA] = (ushort)lp;  Alo[aB] = (ushort)(lp >> 16);
    };
    // store jet of (neuron n, point p=2g+e): channel pairs at rows 16cp+4g+2e, +1
    auto store_jet6 = [&](const float d[6], int e, int n) {
        #pragma unroll
        for (int cp = 0; cp < 3; ++cp) {
            const int rowA = 16 * cp + 4 * g + 2 * e;
            put_pair(d[2 * cp], d[2 * cp + 1], rowA, n);
        }
    };

    // ---- layer 0: closed-form 6-jets; lane: 2 neurons x 2 points ----
    #pragma unroll
    for (int ct = 0; ct < 2; ++ct) {
        const int n = n0 + 16 * ct;
        float w0 = args.W0[n * 3], w1 = args.W0[n * 3 + 1], w2 = args.W0[n * 3 + 2];
        float bb = args.b0[n];
        #pragma unroll
        for (int e = 0; e < 2; ++e) {
            const int p = 2 * g + e;
            float x = args.xs[pbase + p], y = args.ys[pbase + p], tt = args.ts[pbase + p];
            float d[6];
            d[0] = w0 * x + w1 * y + w2 * tt + bb;
            d[1] = w0; d[2] = w1; d[3] = w2;
            d[4] = 0.f; d[5] = 0.f;
            tanh_jet6(d);
            store_jet6(d, e, n);
        }
    }
    __syncthreads();

    for (int L = 1; L <= 7; ++L) {
        const u32x4* whi = args.wpk16 + (size_t)(L - 1) * 4096;
        const u32x4* wlo = whi + 2048;
        f32x4 acc00{}, acc01{}, acc02{};   // ct=0, rt=0..2
        f32x4 acc10{}, acc11{}, acc12{};   // ct=1

        #pragma unroll
        for (int s = 0; s < 4; ++s) {
            const int gb = s * 4 + g;               // k-granule 0..15
            const u32x4 rbh0 = whi[gb * 128 + n0];
            const u32x4 rbh1 = whi[gb * 128 + n0 + 16];
            const u32x4 rbl0 = wlo[gb * 128 + n0];
            const u32x4 rbl1 = wlo[gb * 128 + n0 + 16];

            const int koff = (gb ^ l15) << 3;
            bf16x8 ah0 = __builtin_bit_cast(bf16x8, *(const u32x4*)&Ahi[(     l15) * 128 + koff]);
            bf16x8 ah1 = __builtin_bit_cast(bf16x8, *(const u32x4*)&Ahi[(16 + l15) * 128 + koff]);
            bf16x8 ah2 = __builtin_bit_cast(bf16x8, *(const u32x4*)&Ahi[(32 + l15) * 128 + koff]);
            bf16x8 al0 = __builtin_bit_cast(bf16x8, *(const u32x4*)&Alo[(     l15) * 128 + koff]);
            bf16x8 al1 = __builtin_bit_cast(bf16x8, *(const u32x4*)&Alo[(16 + l15) * 128 + koff]);
            bf16x8 al2 = __builtin_bit_cast(bf16x8, *(const u32x4*)&Alo[(32 + l15) * 128 + koff]);
            bf16x8 bh0 = __builtin_bit_cast(bf16x8, rbh0);
            bf16x8 bh1 = __builtin_bit_cast(bf16x8, rbh1);
            bf16x8 bl0 = __builtin_bit_cast(bf16x8, rbl0);
            bf16x8 bl1 = __builtin_bit_cast(bf16x8, rbl1);

            acc00 = mfma16(ah0, bh0, acc00);
            acc01 = mfma16(ah1, bh0, acc01);
            acc02 = mfma16(ah2, bh0, acc02);
            acc10 = mfma16(ah0, bh1, acc10);
            acc11 = mfma16(ah1, bh1, acc11);
            acc12 = mfma16(ah2, bh1, acc12);
            acc00 = mfma16(al0, bh0, acc00);
            acc01 = mfma16(al1, bh0, acc01);
            acc02 = mfma16(al2, bh0, acc02);
            acc10 = mfma16(al0, bh1, acc10);
            acc11 = mfma16(al1, bh1, acc11);
            acc12 = mfma16(al2, bh1, acc12);
            acc00 = mfma16(ah0, bl0, acc00);
            acc01 = mfma16(ah1, bl0, acc01);
            acc02 = mfma16(ah2, bl0, acc02);
            acc10 = mfma16(ah0, bl1, acc10);
            acc11 = mfma16(ah1, bl1, acc11);
            acc12 = mfma16(ah2, bl1, acc12);
        }

        __syncthreads();   // all waves finished reading A

        if (L < 7) {
            #pragma unroll
            for (int ct = 0; ct < 2; ++ct) {
                const int n = n0 + 16 * ct;
                const float bL = args.bias[L][n];
                #pragma unroll
                for (int e = 0; e < 2; ++e) {
                    float d[6];
                    if (ct == 0) {
                        d[0] = acc00[2 * e]; d[1] = acc00[1 + 2 * e];
                        d[2] = acc01[2 * e]; d[3] = acc01[1 + 2 * e];
                        d[4] = acc02[2 * e]; d[5] = acc02[1 + 2 * e];
                    } else {
                        d[0] = acc10[2 * e]; d[1] = acc10[1 + 2 * e];
                        d[2] = acc11[2 * e]; d[3] = acc11[1 + 2 * e];
                        d[4] = acc12[2 * e]; d[5] = acc12[1 + 2 * e];
                    }
                    d[0] += bL;
                    tanh_jet6(d);
                    store_jet6(d, e, n);
                }
            }
            __syncthreads();   // A ready for next layer
        } else {
            #pragma unroll
            for (int e = 0; e < 2; ++e) {
                float rp[9];
                #pragma unroll
                for (int v = 0; v < 9; ++v) rp[v] = 0.f;
                #pragma unroll
                for (int ct = 0; ct < 2; ++ct) {
                    const int n = n0 + 16 * ct;
                    const float bL = args.bias[7][n];
                    const float wp = args.W8[n], wq = args.W8[128 + n];
                    float d[6];
                    if (ct == 0) {
                        d[0] = acc00[2 * e]; d[1] = acc00[1 + 2 * e];
                        d[2] = acc01[2 * e]; d[3] = acc01[1 + 2 * e];
                        d[4] = acc02[2 * e]; d[5] = acc02[1 + 2 * e];
                    } else {
                        d[0] = acc10[2 * e]; d[1] = acc10[1 + 2 * e];
                        d[2] = acc11[2 * e]; d[3] = acc11[1 + 2 * e];
                        d[4] = acc12[2 * e]; d[5] = acc12[1 + 2 * e];
                    }
                    d[0] += bL;
                    tanh_jet6(d);
                    #pragma unroll
                    for (int c = 0; c < 6; ++c) rp[c] += wp * d[c];
                    rp[6] += wq * d[0]; rp[7] += wq * d[1]; rp[8] += wq * d[2];
                }
                #pragma unroll
                for (int v = 0; v < 9; ++v) {
                    float sv = rp[v];
                    sv += __shfl_xor(sv, 8); sv += __shfl_xor(sv, 4);
                    sv += __shfl_xor(sv, 2); sv += __shfl_xor(sv, 1);
                    rp[v] = sv;
                }
                if (l15 == 0) {
                    #pragma unroll
                    for (int v = 0; v < 9; ++v) Part[wid][g][e][v] = rp[v];
                }
            }
        }
    }

    __syncthreads();   // Part visible

    if (tid < 8) {
        const int p = tid, gg = p >> 1, e = p & 1;
        float s[9];
        #pragma unroll
        for (int v = 0; v < 9; ++v)
            s[v] = Part[0][gg][e][v] + Part[1][gg][e][v]
                 + Part[2][gg][e][v] + Part[3][gg][e][v];

        float u   = s[2];              // psi_y
        float v   = -s[1];             // -psi_x
        float pv  = s[6] + args.b8[1]; // p
        float f_u = s[5] + s[7];       // psi_yt + p_x      (lambda = 0)
        float f_v = -s[4] + s[8];      // -psi_xt + p_y
        const int pt = pbase + p;
        float* out = args.out;
        out[0 * NPTS + pt] = u;
        out[1 * NPTS + pt] = v;
        out[2 * NPTS + pt] = pv;
        out[3 * NPTS + pt] = f_u;
        out[4 * NPTS + pt] = f_v;
    }
}

// ================= full path (R7-verified), runs only when lambda != 0 =========
__global__ __launch_bounds__(256, 2)
void pinn_mfma6_kernel(Args args)
{
    if (args.l1[0] == 0.f && args.l2[0] == 0.f) return;   // reduced path handles it

    __shared__ ushort Ahi[128 * 128];       // 32 KB
    __shared__ ushort Alo[128 * 128];       // 32 KB
    __shared__ float  Part[4][2][4][16];    // 2 KB

    const int tid   = threadIdx.x;
    const int lane  = tid & 63;
    const int wid   = tid >> 6;
    const int ln31  = lane & 31;
    const int kh    = lane >> 5;
    const int n     = wid * 32 + ln31;
    const int pbase = blockIdx.x * 8;

    auto store_jet = [&](const float d[13], int j) {
        const int rb = 32 * j + 4 * kh;
        #pragma unroll
        for (int cp = 0; cp < 6; ++cp) {
            const int cA = 2 * cp, cB = cA + 1;
            const int rowA = rb + 8 * (cA >> 2) + (cA & 3);
            const int rowB = rb + 8 * (cB >> 2) + (cB & 3);
            const int aA = rowA * 128 + ((((n >> 3) ^ (rowA & 15)) << 3) | (n & 7));
            const int aB = rowB * 128 + ((((n >> 3) ^ (rowB & 15)) << 3) | (n & 7));
            uint32_t hp = cvtpk_bf16(d[cA], d[cB]);
            float hA = __uint_as_float(hp << 16);
            float hB = __uint_as_float(hp & 0xFFFF0000u);
            uint32_t lp = cvtpk_bf16(d[cA] - hA, d[cB] - hB);
            Ahi[aA] = (ushort)hp; Ahi[aB] = (ushort)(hp >> 16);
            Alo[aA] = (ushort)lp; Alo[aB] = (ushort)(lp >> 16);
        }
        {
            const int row = rb + 24;
            const int a12 = row * 128 + ((((n >> 3) ^ (row & 15)) << 3) | (n & 7));
            uint32_t hp = cvtpk_bf16(d[12], 0.f);
            float h = __uint_as_float(hp << 16);
            uint32_t lp = cvtpk_bf16(d[12] - h, 0.f);
            Ahi[a12] = (ushort)hp;
            Alo[a12] = (ushort)lp;
        }
    };

    {
        float w0 = args.W0[n * 3], w1 = args.W0[n * 3 + 1], w2 = args.W0[n * 3 + 2];
        float bb = args.b0[n];
        #pragma unroll
        for (int j = 0; j < 4; ++j) {
            const int p = j + 4 * kh;
            float x = args.xs[pbase + p], y = args.ys[pbase + p], t = args.ts[pbase + p];
            float d[13];
            #pragma unroll
            for (int c = 4; c < 13; ++c) d[c] = 0.f;
            d[0] = w0 * x + w1 * y + w2 * t + bb;
            d[1] = w0; d[2] = w1; d[3] = w2;
            tanh_jet(d);
            store_jet(d, j);
        }
        #pragma unroll
        for (int i = 0; i < 12; ++i) {
            int idx  = tid + 256 * i;
            int pl   = (idx >= 1536) ? 1 : 0;
            int rem  = idx - 1536 * pl;
            int rowi = rem >> 6;
            int w    = rem & 63;
            int t4   = rowi / 6, s = rowi - 6 * t4;
            int row  = 32 * t4 + 24 + 4 * (s / 3) + 1 + (s % 3);
            uint32_t* P = pl ? (uint32_t*)Alo : (uint32_t*)Ahi;
            P[row * 64 + w] = 0;
        }
    }
    __syncthreads();

    for (int L = 1; L <= 7; ++L) {
        const u32x4* whi = args.wpk + (size_t)(L - 1) * 4096;
        const u32x4* wlo = whi + 2048;
        f32x16 acc0{}, acc1{}, acc2{}, acc3{};

        #pragma unroll
        for (int ks = 0; ks < 8; ++ks) {
            const int kb = ks * 2 + kh;
            const u32x4 rbh = whi[kb * 128 + n];
            const u32x4 rbl = wlo[kb * 128 + n];

            const int koff = (kb ^ (ln31 & 15)) << 3;
            const int e0 = (ln31      ) * 128 + koff;
            const int e1 = (ln31 + 32 ) * 128 + koff;
            const int e2 = (ln31 + 64 ) * 128 + koff;
            const int e3 = (ln31 + 96 ) * 128 + koff;
            bf16x8 ah0 = __builtin_bit_cast(bf16x8, *(const u32x4*)&Ahi[e0]);
            bf16x8 ah1 = __builtin_bit_cast(bf16x8, *(const u32x4*)&Ahi[e1]);
            bf16x8 ah2 = __builtin_bit_cast(bf16x8, *(const u32x4*)&Ahi[e2]);
            bf16x8 ah3 = __builtin_bit_cast(bf16x8, *(const u32x4*)&Ahi[e3]);
            bf16x8 al0 = __builtin_bit_cast(bf16x8, *(const u32x4*)&Alo[e0]);
            bf16x8 al1 = __builtin_bit_cast(bf16x8, *(const u32x4*)&Alo[e1]);
            bf16x8 al2 = __builtin_bit_cast(bf16x8, *(const u32x4*)&Alo[e2]);
            bf16x8 al3 = __builtin_bit_cast(bf16x8, *(const u32x4*)&Alo[e3]);
            bf16x8 bh  = __builtin_bit_cast(bf16x8, rbh);
            bf16x8 bl  = __builtin_bit_cast(bf16x8, rbl);

            acc0 = mfma32(ah0, bh, acc0);
            acc1 = mfma32(ah1, bh, acc1);
            acc2 = mfma32(ah2, bh, acc2);
            acc3 = mfma32(ah3, bh, acc3);
            acc0 = mfma32(al0, bh, acc0);
            acc1 = mfma32(al1, bh, acc1);
            acc2 = mfma32(al2, bh, acc2);
            acc3 = mfma32(al3, bh, acc3);
            acc0 = mfma32(ah0, bl, acc0);
            acc1 = mfma32(ah1, bl, acc1);
            acc2 = mfma32(ah2, bl, acc2);
            acc3 = mfma32(ah3, bl, acc3);
        }

        __syncthreads();

        const float bL = args.bias[L][n];

        if (L < 7) {
            #pragma unroll
            for (int j = 0; j < 4; ++j) {
                float d[13];
                #pragma unroll
                for (int c = 0; c < 13; ++c)
                    d[c] = (j == 0) ? acc0[c] : (j == 1) ? acc1[c] : (j == 2) ? acc2[c] : acc3[c];
                d[0] += bL;
                tanh_jet(d);
                store_jet(d, j);
            }
            __syncthreads();
        } else {
            const float wp = args.W8[n], wq = args.W8[128 + n];
            #pragma unroll
            for (int j = 0; j < 4; ++j) {
                float d[13];
                #pragma unroll
                for (int c = 0; c < 13; ++c)
                    d[c] = (j == 0) ? acc0[c] : (j == 1) ? acc1[c] : (j == 2) ? acc2[c] : acc3[c];
                d[0] += bL;
                tanh_jet(d);
                float rp[16];
                #pragma unroll
                for (int c = 0; c < 13; ++c) rp[c] = wp * d[c];
                rp[13] = wq * d[0]; rp[14] = wq * d[1]; rp[15] = wq * d[2];
                #pragma unroll
                for (int v = 0; v < 16; ++v) {
                    float s = rp[v];
                    s += __shfl_xor(s, 16); s += __shfl_xor(s, 8);
                    s += __shfl_xor(s, 4);  s += __shfl_xor(s, 2);
                    s += __shfl_xor(s, 1);
                    rp[v] = s;
                }
                if (ln31 == 0) {
                    #pragma unroll
                    for (int v = 0; v < 16; ++v) Part[wid][kh][j][v] = rp[v];
                }
            }
        }
    }

    __syncthreads();

    if (tid < 8) {
        const int p = tid, khp = p >> 2, jp = p & 3;
        float s[16];
        #pragma unroll
        for (int v = 0; v < 16; ++v)
            s[v] = Part[0][khp][jp][v] + Part[1][khp][jp][v]
                 + Part[2][khp][jp][v] + Part[3][khp][jp][v];

        float l1 = args.l1[0], l2 = args.l2[0];
        float u    = s[2];
        float v    = -s[1];
        float pv   = s[13] + args.b8[1];
        float u_t  = s[8];
        float v_t  = -s[7];
        float u_x  = s[5];
        float u_y  = s[6];
        float v_x  = -s[4];
        float v_y  = -s[5];
        float u_xx = s[10];
        float u_yy = s[12];
        float v_xx = -s[9];
        float v_yy = -s[11];
        float p_x = s[14], p_y = s[15];
        float f_u = u_t + l1 * (u * u_x + v * u_y) + p_x - l2 * (u_xx + u_yy);
        float f_v = v_t + l1 * (u * v_x + v * v_y) + p_y - l2 * (v_xx + v_yy);
        const int pt = pbase + p;
        float* out = args.out;
        out[0 * NPTS + pt] = u;
        out[1 * NPTS + pt] = v;
        out[2 * NPTS + pt] = pv;
        out[3 * NPTS + pt] = f_u;
        out[4 * NPTS + pt] = f_v;
    }
}

extern "C" void kernel_launch(void* const* d_in, const int* in_sizes, int n_in,
                              void* d_out, int out_size, void* d_ws, size_t ws_size,
                              hipStream_t stream) {
    const float* l1p = (const float*)d_in[21];
    const float* l2p = (const float*)d_in[22];

    // new 16x16 format at d_ws (448 KB), old 32x32 format at d_ws+448KB
    u32x4* wpk16 = (u32x4*)d_ws;
    u32x4* wpkOld = (u32x4*)((char*)d_ws + 448 * 1024);

    PrepArgs pa16;
    for (int i = 0; i < 7; ++i) pa16.W[i] = (const float*)d_in[2 * (i + 1)];
    pa16.dst = wpk16; pa16.l1 = l1p; pa16.l2 = l2p; pa16.run_on_zero = 1;
    pack_w16_kernel<<<56, 256, 0, stream>>>(pa16);

    PrepArgs paOld = pa16;
    paOld.dst = wpkOld; paOld.run_on_zero = 0;
    pack_w_kernel<<<56, 256, 0, stream>>>(paOld);

    Args a;
    a.W0 = (const float*)d_in[0];
    a.b0 = (const float*)d_in[1];
    a.bias[0] = nullptr;
    for (int L = 1; L <= 7; ++L) a.bias[L] = (const float*)d_in[2 * L + 1];
    a.W8 = (const float*)d_in[16];
    a.b8 = (const float*)d_in[17];
    a.xs = (const float*)d_in[18];
    a.ys = (const float*)d_in[19];
    a.ts = (const float*)d_in[20];
    a.l1 = l1p;
    a.l2 = l2p;
    a.wpk = wpkOld;
    a.wpk16 = wpk16;
    a.out = (float*)d_out;

    pinn_red8_kernel<<<NPTS / 8, 256, 0, stream>>>(a);    // runs iff lambda == 0
    pinn_mfma6_kernel<<<NPTS / 8, 256, 0, stream>>>(a);   // runs iff lambda != 0
}

// Round 11
// 82.774 us; speedup vs baseline: 1.7790x; 1.7790x over previous
//
#include <hip/hip_runtime.h>
#include <stdint.h>

#define NPTS 16384

typedef __attribute__((ext_vector_type(8)))  __bf16   bf16x8;
typedef __attribute__((ext_vector_type(16))) float    f32x16;
typedef __attribute__((ext_vector_type(4)))  float    f32x4;
typedef __attribute__((ext_vector_type(4)))  uint32_t u32x4;

struct PrepArgs {
    const float* W[7];
    u32x4* dst;
    const float* l1; const float* l2;
    int run_on_zero;   // 1: run iff lambda==0; 0: run iff lambda!=0
};

struct Args {
    const float* W0; const float* b0;
    const float* bias[8];   // [1..7] valid
    const float* W8; const float* b8;
    const float* xs; const float* ys; const float* ts;
    const float* l1; const float* l2;
    const u32x4* wpk;       // packed W frags, 32x32 format (fallback)
    const u32x4* wpk16;     // packed W frags, 16x16 format (reduced path)
    float* out;
};

// ---------- bf16 helpers (verified) ----------
__device__ __forceinline__ uint32_t b16rne(float x) {
    uint32_t u = __float_as_uint(x);
    return (u + 0x7FFFu + ((u >> 16) & 1u)) >> 16;
}
__device__ __forceinline__ float fromb16(uint32_t h) { return __uint_as_float(h << 16); }

__device__ __forceinline__ void packPair(float a, float b, uint32_t& hw, uint32_t& lw) {
    uint32_t ha = b16rne(a), hb = b16rne(b);
    float la = a - fromb16(ha), lb = b - fromb16(hb);
    hw = ha | (hb << 16);
    lw = b16rne(la) | (b16rne(lb) << 16);
}

// packed RNE bf16 pair: low16 = bf16(a), high16 = bf16(b)
__device__ __forceinline__ uint32_t cvtpk_bf16(float a, float b) {
    uint32_t r;
    asm("v_cvt_pk_bf16_f32 %0, %1, %2" : "=v"(r) : "v"(a), "v"(b));
    return r;
}

__device__ __forceinline__ f32x16 mfma32(bf16x8 a, bf16x8 b, f32x16 c) {
    return __builtin_amdgcn_mfma_f32_32x32x16_bf16(a, b, c, 0, 0, 0);
}
__device__ __forceinline__ f32x4 mfma16(bf16x8 a, bf16x8 b, f32x4 c) {
    return __builtin_amdgcn_mfma_f32_16x16x32_bf16(a, b, c, 0, 0, 0);
}

__device__ __forceinline__ float fast_tanh(float x) {
    float e = __expf(2.0f * x);
    return 1.0f - __fdividef(2.0f, e + 1.0f);   // inf-safe
}

// ---------- full 13-channel tanh jet (verified, fallback path) ----------
__device__ __forceinline__ void tanh_jet(float u[13]) {
    float s    = fast_tanh(u[0]);
    float sp   = 1.f - s * s;
    float spp  = -2.f * s * sp;
    float sppp = -2.f * (sp * sp + s * spp);
    float u1 = u[1], u2 = u[2], u3 = u[3];
    float u4 = u[4], u5 = u[5], u6 = u[6];
    u[0] = s;
    u[1] = sp * u1;
    u[2] = sp * u2;
    u[3] = sp * u3;
    u[9]  = sppp * u1 * u1 * u1 + 3.f * spp * u1 * u4 + sp * u[9];
    u[10] = sppp * u1 * u1 * u2 + spp * (u4 * u2 + 2.f * u5 * u1) + sp * u[10];
    u[11] = sppp * u1 * u2 * u2 + spp * (u6 * u1 + 2.f * u5 * u2) + sp * u[11];
    u[12] = sppp * u2 * u2 * u2 + 3.f * spp * u2 * u6 + sp * u[12];
    u[4] = spp * u1 * u1 + sp * u4;
    u[5] = spp * u1 * u2 + sp * u5;
    u[6] = spp * u2 * u2 + sp * u6;
    u[7] = spp * u1 * u3 + sp * u[7];
    u[8] = spp * u2 * u3 + sp * u[8];
}

// ---------- reduced 6-channel jet: 0:val 1:dx 2:dy 3:dt 4:dxt 5:dyt ----------
__device__ __forceinline__ void tanh_jet6(float u[6]) {
    float s   = fast_tanh(u[0]);
    float sp  = 1.f - s * s;
    float spp = -2.f * s * sp;
    float u1 = u[1], u2 = u[2], u3 = u[3];
    u[0] = s;
    u[4] = spp * u1 * u3 + sp * u[4];
    u[5] = spp * u2 * u3 + sp * u[5];
    u[1] = sp * u1;
    u[2] = sp * u2;
    u[3] = sp * u3;
}

// ---------- prep A: 32x32 B-frag order (fallback format, verified) ----------
__global__ __launch_bounds__(256)
void pack_w_kernel(PrepArgs a) {
    bool z = (a.l1[0] == 0.f && a.l2[0] == 0.f);
    if (z != (bool)a.run_on_zero) return;
    int idx = blockIdx.x * 256 + threadIdx.x;   // 7*16*128 = 14336
    int L  = idx >> 11;
    int kb = (idx >> 7) & 15;
    int n  = idx & 127;
    const float* w = a.W[L] + n * 128 + kb * 8;
    float4 f0 = *(const float4*)w;
    float4 f1 = *(const float4*)(w + 4);
    uint32_t h0, h1, h2, h3, l0, l1, l2, l3;
    packPair(f0.x, f0.y, h0, l0);
    packPair(f0.z, f0.w, h1, l1);
    packPair(f1.x, f1.y, h2, l2);
    packPair(f1.z, f1.w, h3, l3);
    a.dst[((L * 2 + 0) * 16 + kb) * 128 + n] = u32x4{h0, h1, h2, h3};
    a.dst[((L * 2 + 1) * 16 + kb) * 128 + n] = u32x4{l0, l1, l2, l3};
}

// ---------- prep B: 16x16 B-frag order (reduced path, R10-verified) ----------
// dst[((L*2+h)*16 + s*4+g)*128 + n] = u32x4 of bf16 pairs W[n][32s+8g+0..7]
__global__ __launch_bounds__(256)
void pack_w16_kernel(PrepArgs a) {
    bool z = (a.l1[0] == 0.f && a.l2[0] == 0.f);
    if (z != (bool)a.run_on_zero) return;
    int idx = blockIdx.x * 256 + threadIdx.x;   // 7*4*4*128 = 14336
    int L = idx >> 11;
    int s = (idx >> 9) & 3;
    int g = (idx >> 7) & 3;
    int n = idx & 127;
    const float* w = a.W[L] + n * 128 + s * 32 + g * 8;
    float4 f0 = *(const float4*)w;
    float4 f1 = *(const float4*)(w + 4);
    uint32_t h0, h1, h2, h3, l0, l1, l2, l3;
    packPair(f0.x, f0.y, h0, l0);
    packPair(f0.z, f0.w, h1, l1);
    packPair(f1.x, f1.y, h2, l2);
    packPair(f1.z, f1.w, h3, l3);
    a.dst[((L * 2 + 0) * 16 + s * 4 + g) * 128 + n] = u32x4{h0, h1, h2, h3};
    a.dst[((L * 2 + 1) * 16 + s * 4 + g) * 128 + n] = u32x4{l0, l1, l2, l3};
}

// ================= reduced path: lambda1 == lambda2 == 0 =================
// R10-verified geometry; only the launch-bounds (VGPR budget) changed.
// 8 points/block, M=48 rows = exactly 3 16-row MFMA tiles, zero pad.
// Row map: row(c,p) = 16*(c>>1) + 4*(p>>1) + (c&1) + 2*(p&1).
// 16x16x32 MFMA, C: col=lane&15, row=(lane>>4)*4+reg [m89-verified] =>
// lane (l15,g) holds, for neurons n0=wid*32+l15 and n0+16, the complete
// 6-channel jets of points p=2g+e at static acc indices.
// A: two bf16 planes [48][128], 16B-granule XOR swizzle (verified):
//   addr(row,k) = row*128 + (((k>>3) ^ (row&15))<<3) + (k&7)
__global__ __launch_bounds__(256, 4)   // R10's (256,6) caused spills: VGPR 40, 53MB scratch writes
void pinn_red8_kernel(Args args)
{
    if (args.l1[0] != 0.f || args.l2[0] != 0.f) return;   // uniform guard

    __shared__ ushort Ahi[48 * 128];        // 12 KB
    __shared__ ushort Alo[48 * 128];        // 12 KB
    __shared__ float  Part[4][4][2][9];     // 1.125 KB [wid][g][e][v]

    const int tid   = threadIdx.x;
    const int lane  = tid & 63;
    const int wid   = tid >> 6;
    const int l15   = lane & 15;
    const int g     = lane >> 4;            // 0..3
    const int n0    = wid * 32 + l15;       // ct=0 neuron; ct=1 -> +16
    const int pbase = blockIdx.x * 8;

    auto put_pair = [&](float dA, float dB, int rowA, int n) {
        const int rowB = rowA + 1;
        const int aA = rowA * 128 + ((((n >> 3) ^ (rowA & 15)) << 3) | (n & 7));
        const int aB = rowB * 128 + ((((n >> 3) ^ (rowB & 15)) << 3) | (n & 7));
        uint32_t hp = cvtpk_bf16(dA, dB);
        float hA = __uint_as_float(hp << 16);
        float hB = __uint_as_float(hp & 0xFFFF0000u);
        uint32_t lp = cvtpk_bf16(dA - hA, dB - hB);
        Ahi[aA] = (ushort)hp;  Ahi[aB] = (ushort)(hp >> 16);
        Alo[aA] = (ushort)lp;  Alo[aB] = (ushort)(lp >> 16);
    };
    // store jet of (neuron n, point p=2g+e): channel pairs at rows 16cp+4g+2e, +1
    auto store_jet6 = [&](const float d[6], int e, int n) {
        #pragma unroll
        for (int cp = 0; cp < 3; ++cp) {
            const int rowA = 16 * cp + 4 * g + 2 * e;
            put_pair(d[2 * cp], d[2 * cp + 1], rowA, n);
        }
    };

    // ---- layer 0: closed-form 6-jets; lane: 2 neurons x 2 points ----
    #pragma unroll
    for (int ct = 0; ct < 2; ++ct) {
        const int n = n0 + 16 * ct;
        float w0 = args.W0[n * 3], w1 = args.W0[n * 3 + 1], w2 = args.W0[n * 3 + 2];
        float bb = args.b0[n];
        #pragma unroll
        for (int e = 0; e < 2; ++e) {
            const int p = 2 * g + e;
            float x = args.xs[pbase + p], y = args.ys[pbase + p], tt = args.ts[pbase + p];
            float d[6];
            d[0] = w0 * x + w1 * y + w2 * tt + bb;
            d[1] = w0; d[2] = w1; d[3] = w2;
            d[4] = 0.f; d[5] = 0.f;
            tanh_jet6(d);
            store_jet6(d, e, n);
        }
    }
    __syncthreads();

    for (int L = 1; L <= 7; ++L) {
        const u32x4* whi = args.wpk16 + (size_t)(L - 1) * 4096;
        const u32x4* wlo = whi + 2048;
        f32x4 acc00{}, acc01{}, acc02{};   // ct=0, rt=0..2
        f32x4 acc10{}, acc11{}, acc12{};   // ct=1

        #pragma unroll
        for (int s = 0; s < 4; ++s) {
            const int gb = s * 4 + g;               // k-granule 0..15
            const u32x4 rbh0 = whi[gb * 128 + n0];
            const u32x4 rbh1 = whi[gb * 128 + n0 + 16];
            const u32x4 rbl0 = wlo[gb * 128 + n0];
            const u32x4 rbl1 = wlo[gb * 128 + n0 + 16];

            const int koff = (gb ^ l15) << 3;
            bf16x8 ah0 = __builtin_bit_cast(bf16x8, *(const u32x4*)&Ahi[(     l15) * 128 + koff]);
            bf16x8 ah1 = __builtin_bit_cast(bf16x8, *(const u32x4*)&Ahi[(16 + l15) * 128 + koff]);
            bf16x8 ah2 = __builtin_bit_cast(bf16x8, *(const u32x4*)&Ahi[(32 + l15) * 128 + koff]);
            bf16x8 al0 = __builtin_bit_cast(bf16x8, *(const u32x4*)&Alo[(     l15) * 128 + koff]);
            bf16x8 al1 = __builtin_bit_cast(bf16x8, *(const u32x4*)&Alo[(16 + l15) * 128 + koff]);
            bf16x8 al2 = __builtin_bit_cast(bf16x8, *(const u32x4*)&Alo[(32 + l15) * 128 + koff]);
            bf16x8 bh0 = __builtin_bit_cast(bf16x8, rbh0);
            bf16x8 bh1 = __builtin_bit_cast(bf16x8, rbh1);
            bf16x8 bl0 = __builtin_bit_cast(bf16x8, rbl0);
            bf16x8 bl1 = __builtin_bit_cast(bf16x8, rbl1);

            acc00 = mfma16(ah0, bh0, acc00);
            acc01 = mfma16(ah1, bh0, acc01);
            acc02 = mfma16(ah2, bh0, acc02);
            acc10 = mfma16(ah0, bh1, acc10);
            acc11 = mfma16(ah1, bh1, acc11);
            acc12 = mfma16(ah2, bh1, acc12);
            acc00 = mfma16(al0, bh0, acc00);
            acc01 = mfma16(al1, bh0, acc01);
            acc02 = mfma16(al2, bh0, acc02);
            acc10 = mfma16(al0, bh1, acc10);
            acc11 = mfma16(al1, bh1, acc11);
            acc12 = mfma16(al2, bh1, acc12);
            acc00 = mfma16(ah0, bl0, acc00);
            acc01 = mfma16(ah1, bl0, acc01);
            acc02 = mfma16(ah2, bl0, acc02);
            acc10 = mfma16(ah0, bl1, acc10);
            acc11 = mfma16(ah1, bl1, acc11);
            acc12 = mfma16(ah2, bl1, acc12);
        }

        __syncthreads();   // all waves finished reading A

        if (L < 7) {
            #pragma unroll
            for (int ct = 0; ct < 2; ++ct) {
                const int n = n0 + 16 * ct;
                const float bL = args.bias[L][n];
                #pragma unroll
                for (int e = 0; e < 2; ++e) {
                    float d[6];
                    if (ct == 0) {
                        d[0] = acc00[2 * e]; d[1] = acc00[1 + 2 * e];
                        d[2] = acc01[2 * e]; d[3] = acc01[1 + 2 * e];
                        d[4] = acc02[2 * e]; d[5] = acc02[1 + 2 * e];
                    } else {
                        d[0] = acc10[2 * e]; d[1] = acc10[1 + 2 * e];
                        d[2] = acc11[2 * e]; d[3] = acc11[1 + 2 * e];
                        d[4] = acc12[2 * e]; d[5] = acc12[1 + 2 * e];
                    }
                    d[0] += bL;
                    tanh_jet6(d);
                    store_jet6(d, e, n);
                }
            }
            __syncthreads();   // A ready for next layer
        } else {
            #pragma unroll
            for (int e = 0; e < 2; ++e) {
                float rp[9];
                #pragma unroll
                for (int v = 0; v < 9; ++v) rp[v] = 0.f;
                #pragma unroll
                for (int ct = 0; ct < 2; ++ct) {
                    const int n = n0 + 16 * ct;
                    const float bL = args.bias[7][n];
                    const float wp = args.W8[n], wq = args.W8[128 + n];
                    float d[6];
                    if (ct == 0) {
                        d[0] = acc00[2 * e]; d[1] = acc00[1 + 2 * e];
                        d[2] = acc01[2 * e]; d[3] = acc01[1 + 2 * e];
                        d[4] = acc02[2 * e]; d[5] = acc02[1 + 2 * e];
                    } else {
                        d[0] = acc10[2 * e]; d[1] = acc10[1 + 2 * e];
                        d[2] = acc11[2 * e]; d[3] = acc11[1 + 2 * e];
                        d[4] = acc12[2 * e]; d[5] = acc12[1 + 2 * e];
                    }
                    d[0] += bL;
                    tanh_jet6(d);
                    #pragma unroll
                    for (int c = 0; c < 6; ++c) rp[c] += wp * d[c];
                    rp[6] += wq * d[0]; rp[7] += wq * d[1]; rp[8] += wq * d[2];
                }
                #pragma unroll
                for (int v = 0; v < 9; ++v) {
                    float sv = rp[v];
                    sv += __shfl_xor(sv, 8); sv += __shfl_xor(sv, 4);
                    sv += __shfl_xor(sv, 2); sv += __shfl_xor(sv, 1);
                    rp[v] = sv;
                }
                if (l15 == 0) {
                    #pragma unroll
                    for (int v = 0; v < 9; ++v) Part[wid][g][e][v] = rp[v];
                }
            }
        }
    }

    __syncthreads();   // Part visible

    if (tid < 8) {
        const int p = tid, gg = p >> 1, e = p & 1;
        float s[9];
        #pragma unroll
        for (int v = 0; v < 9; ++v)
            s[v] = Part[0][gg][e][v] + Part[1][gg][e][v]
                 + Part[2][gg][e][v] + Part[3][gg][e][v];

        float u   = s[2];              // psi_y
        float v   = -s[1];             // -psi_x
        float pv  = s[6] + args.b8[1]; // p
        float f_u = s[5] + s[7];       // psi_yt + p_x      (lambda = 0)
        float f_v = -s[4] + s[8];      // -psi_xt + p_y
        const int pt = pbase + p;
        float* out = args.out;
        out[0 * NPTS + pt] = u;
        out[1 * NPTS + pt] = v;
        out[2 * NPTS + pt] = pv;
        out[3 * NPTS + pt] = f_u;
        out[4 * NPTS + pt] = f_v;
    }
}

// ================= full path (R7-verified), runs only when lambda != 0 =========
__global__ __launch_bounds__(256, 2)
void pinn_mfma6_kernel(Args args)
{
    if (args.l1[0] == 0.f && args.l2[0] == 0.f) return;   // reduced path handles it

    __shared__ ushort Ahi[128 * 128];       // 32 KB
    __shared__ ushort Alo[128 * 128];       // 32 KB
    __shared__ float  Part[4][2][4][16];    // 2 KB

    const int tid   = threadIdx.x;
    const int lane  = tid & 63;
    const int wid   = tid >> 6;
    const int ln31  = lane & 31;
    const int kh    = lane >> 5;
    const int n     = wid * 32 + ln31;
    const int pbase = blockIdx.x * 8;

    auto store_jet = [&](const float d[13], int j) {
        const int rb = 32 * j + 4 * kh;
        #pragma unroll
        for (int cp = 0; cp < 6; ++cp) {
            const int cA = 2 * cp, cB = cA + 1;
            const int rowA = rb + 8 * (cA >> 2) + (cA & 3);
            const int rowB = rb + 8 * (cB >> 2) + (cB & 3);
            const int aA = rowA * 128 + ((((n >> 3) ^ (rowA & 15)) << 3) | (n & 7));
            const int aB = rowB * 128 + ((((n >> 3) ^ (rowB & 15)) << 3) | (n & 7));
            uint32_t hp = cvtpk_bf16(d[cA], d[cB]);
            float hA = __uint_as_float(hp << 16);
            float hB = __uint_as_float(hp & 0xFFFF0000u);
            uint32_t lp = cvtpk_bf16(d[cA] - hA, d[cB] - hB);
            Ahi[aA] = (ushort)hp; Ahi[aB] = (ushort)(hp >> 16);
            Alo[aA] = (ushort)lp; Alo[aB] = (ushort)(lp >> 16);
        }
        {
            const int row = rb + 24;
            const int a12 = row * 128 + ((((n >> 3) ^ (row & 15)) << 3) | (n & 7));
            uint32_t hp = cvtpk_bf16(d[12], 0.f);
            float h = __uint_as_float(hp << 16);
            uint32_t lp = cvtpk_bf16(d[12] - h, 0.f);
            Ahi[a12] = (ushort)hp;
            Alo[a12] = (ushort)lp;
        }
    };

    {
        float w0 = args.W0[n * 3], w1 = args.W0[n * 3 + 1], w2 = args.W0[n * 3 + 2];
        float bb = args.b0[n];
        #pragma unroll
        for (int j = 0; j < 4; ++j) {
            const int p = j + 4 * kh;
            float x = args.xs[pbase + p], y = args.ys[pbase + p], t = args.ts[pbase + p];
            float d[13];
            #pragma unroll
            for (int c = 4; c < 13; ++c) d[c] = 0.f;
            d[0] = w0 * x + w1 * y + w2 * t + bb;
            d[1] = w0; d[2] = w1; d[3] = w2;
            tanh_jet(d);
            store_jet(d, j);
        }
        #pragma unroll
        for (int i = 0; i < 12; ++i) {
            int idx  = tid + 256 * i;
            int pl   = (idx >= 1536) ? 1 : 0;
            int rem  = idx - 1536 * pl;
            int rowi = rem >> 6;
            int w    = rem & 63;
            int t4   = rowi / 6, s = rowi - 6 * t4;
            int row  = 32 * t4 + 24 + 4 * (s / 3) + 1 + (s % 3);
            uint32_t* P = pl ? (uint32_t*)Alo : (uint32_t*)Ahi;
            P[row * 64 + w] = 0;
        }
    }
    __syncthreads();

    for (int L = 1; L <= 7; ++L) {
        const u32x4* whi = args.wpk + (size_t)(L - 1) * 4096;
        const u32x4* wlo = whi + 2048;
        f32x16 acc0{}, acc1{}, acc2{}, acc3{};

        #pragma unroll
        for (int ks = 0; ks < 8; ++ks) {
            const int kb = ks * 2 + kh;
            const u32x4 rbh = whi[kb * 128 + n];
            const u32x4 rbl = wlo[kb * 128 + n];

            const int koff = (kb ^ (ln31 & 15)) << 3;
            const int e0 = (ln31      ) * 128 + koff;
            const int e1 = (ln31 + 32 ) * 128 + koff;
            const int e2 = (ln31 + 64 ) * 128 + koff;
            const int e3 = (ln31 + 96 ) * 128 + koff;
            bf16x8 ah0 = __builtin_bit_cast(bf16x8, *(const u32x4*)&Ahi[e0]);
            bf16x8 ah1 = __builtin_bit_cast(bf16x8, *(const u32x4*)&Ahi[e1]);
            bf16x8 ah2 = __builtin_bit_cast(bf16x8, *(const u32x4*)&Ahi[e2]);
            bf16x8 ah3 = __builtin_bit_cast(bf16x8, *(const u32x4*)&Ahi[e3]);
            bf16x8 al0 = __builtin_bit_cast(bf16x8, *(const u32x4*)&Alo[e0]);
            bf16x8 al1 = __builtin_bit_cast(bf16x8, *(const u32x4*)&Alo[e1]);
            bf16x8 al2 = __builtin_bit_cast(bf16x8, *(const u32x4*)&Alo[e2]);
            bf16x8 al3 = __builtin_bit_cast(bf16x8, *(const u32x4*)&Alo[e3]);
            bf16x8 bh  = __builtin_bit_cast(bf16x8, rbh);
            bf16x8 bl  = __builtin_bit_cast(bf16x8, rbl);

            acc0 = mfma32(ah0, bh, acc0);
            acc1 = mfma32(ah1, bh, acc1);
            acc2 = mfma32(ah2, bh, acc2);
            acc3 = mfma32(ah3, bh, acc3);
            acc0 = mfma32(al0, bh, acc0);
            acc1 = mfma32(al1, bh, acc1);
            acc2 = mfma32(al2, bh, acc2);
            acc3 = mfma32(al3, bh, acc3);
            acc0 = mfma32(ah0, bl, acc0);
            acc1 = mfma32(ah1, bl, acc1);
            acc2 = mfma32(ah2, bl, acc2);
            acc3 = mfma32(ah3, bl, acc3);
        }

        __syncthreads();

        const float bL = args.bias[L][n];

        if (L < 7) {
            #pragma unroll
            for (int j = 0; j < 4; ++j) {
                float d[13];
                #pragma unroll
                for (int c = 0; c < 13; ++c)
                    d[c] = (j == 0) ? acc0[c] : (j == 1) ? acc1[c] : (j == 2) ? acc2[c] : acc3[c];
                d[0] += bL;
                tanh_jet(d);
                store_jet(d, j);
            }
            __syncthreads();
        } else {
            const float wp = args.W8[n], wq = args.W8[128 + n];
            #pragma unroll
            for (int j = 0; j < 4; ++j) {
                float d[13];
                #pragma unroll
                for (int c = 0; c < 13; ++c)
                    d[c] = (j == 0) ? acc0[c] : (j == 1) ? acc1[c] : (j == 2) ? acc2[c] : acc3[c];
                d[0] += bL;
                tanh_jet(d);
                float rp[16];
                #pragma unroll
                for (int c = 0; c < 13; ++c) rp[c] = wp * d[c];
                rp[13] = wq * d[0]; rp[14] = wq * d[1]; rp[15] = wq * d[2];
                #pragma unroll
                for (int v = 0; v < 16; ++v) {
                    float s = rp[v];
                    s += __shfl_xor(s, 16); s += __shfl_xor(s, 8);
                    s += __shfl_xor(s, 4);  s += __shfl_xor(s, 2);
                    s += __shfl_xor(s, 1);
                    rp[v] = s;
                }
                if (ln31 == 0) {
                    #pragma unroll
                    for (int v = 0; v < 16; ++v) Part[wid][kh][j][v] = rp[v];
                }
            }
        }
    }

    __syncthreads();

    if (tid < 8) {
        const int p = tid, khp = p >> 2, jp = p & 3;
        float s[16];
        #pragma unroll
        for (int v = 0; v < 16; ++v)
            s[v] = Part[0][khp][jp][v] + Part[1][khp][jp][v]
                 + Part[2][khp][jp][v] + Part[3][khp][jp][v];

        float l1 = args.l1[0], l2 = args.l2[0];
        float u    = s[2];
        float v    = -s[1];
        float pv   = s[13] + args.b8[1];
        float u_t  = s[8];
        float v_t  = -s[7];
        float u_x  = s[5];
        float u_y  = s[6];
        float v_x  = -s[4];
        float v_y  = -s[5];
        float u_xx = s[10];
        float u_yy = s[12];
        float v_xx = -s[9];
        float v_yy = -s[11];
        float p_x = s[14], p_y = s[15];
        float f_u = u_t + l1 * (u * u_x + v * u_y) + p_x - l2 * (u_xx + u_yy);
        float f_v = v_t + l1 * (u * v_x + v * v_y) + p_y - l2 * (v_xx + v_yy);
        const int pt = pbase + p;
        float* out = args.out;
        out[0 * NPTS + pt] = u;
        out[1 * NPTS + pt] = v;
        out[2 * NPTS + pt] = pv;
        out[3 * NPTS + pt] = f_u;
        out[4 * NPTS + pt] = f_v;
    }
}

extern "C" void kernel_launch(void* const* d_in, const int* in_sizes, int n_in,
                              void* d_out, int out_size, void* d_ws, size_t ws_size,
                              hipStream_t stream) {
    const float* l1p = (const float*)d_in[21];
    const float* l2p = (const float*)d_in[22];

    // 16x16 format at d_ws (448 KB), 32x32 format at d_ws+448KB
    u32x4* wpk16 = (u32x4*)d_ws;
    u32x4* wpkOld = (u32x4*)((char*)d_ws + 448 * 1024);

    PrepArgs pa16;
    for (int i = 0; i < 7; ++i) pa16.W[i] = (const float*)d_in[2 * (i + 1)];
    pa16.dst = wpk16; pa16.l1 = l1p; pa16.l2 = l2p; pa16.run_on_zero = 1;
    pack_w16_kernel<<<56, 256, 0, stream>>>(pa16);

    PrepArgs paOld = pa16;
    paOld.dst = wpkOld; paOld.run_on_zero = 0;
    pack_w_kernel<<<56, 256, 0, stream>>>(paOld);

    Args a;
    a.W0 = (const float*)d_in[0];
    a.b0 = (const float*)d_in[1];
    a.bias[0] = nullptr;
    for (int L = 1; L <= 7; ++L) a.bias[L] = (const float*)d_in[2 * L + 1];
    a.W8 = (const float*)d_in[16];
    a.b8 = (const float*)d_in[17];
    a.xs = (const float*)d_in[18];
    a.ys = (const float*)d_in[19];
    a.ts = (const float*)d_in[20];
    a.l1 = l1p;
    a.l2 = l2p;
    a.wpk = wpkOld;
    a.wpk16 = wpk16;
    a.out = (float*)d_out;

    pinn_red8_kernel<<<NPTS / 8, 256, 0, stream>>>(a);    // runs iff lambda == 0
    pinn_mfma6_kernel<<<NPTS / 8, 256, 0, stream>>>(a);   // runs iff lambda != 0
}

// Round 13
// 82.589 us; speedup vs baseline: 1.7830x; 1.0022x over previous
//
#include <hip/hip_runtime.h>
#include <stdint.h>

#define NPTS 16384

typedef __attribute__((ext_vector_type(8)))  __bf16   bf16x8;
typedef __attribute__((ext_vector_type(16))) float    f32x16;
typedef __attribute__((ext_vector_type(4)))  float    f32x4;
typedef __attribute__((ext_vector_type(4)))  uint32_t u32x4;

struct PrepArgs {
    const float* W[7];
    u32x4* dst;
    const float* l1; const float* l2;
    int run_on_zero;   // 1: run iff lambda==0; 0: run iff lambda!=0
};

struct Args {
    const float* W0; const float* b0;
    const float* bias[8];   // [1..7] valid
    const float* W8; const float* b8;
    const float* xs; const float* ys; const float* ts;
    const float* l1; const float* l2;
    const u32x4* wpk;       // packed W frags, 32x32 format (fallback)
    const u32x4* wpk16;     // packed W frags, 16x16 format (reduced path)
    float* out;
};

// ---------- bf16 helpers (verified) ----------
__device__ __forceinline__ uint32_t b16rne(float x) {
    uint32_t u = __float_as_uint(x);
    return (u + 0x7FFFu + ((u >> 16) & 1u)) >> 16;
}
__device__ __forceinline__ float fromb16(uint32_t h) { return __uint_as_float(h << 16); }

__device__ __forceinline__ void packPair(float a, float b, uint32_t& hw, uint32_t& lw) {
    uint32_t ha = b16rne(a), hb = b16rne(b);
    float la = a - fromb16(ha), lb = b - fromb16(hb);
    hw = ha | (hb << 16);
    lw = b16rne(la) | (b16rne(lb) << 16);
}

// packed RNE bf16 pair: low16 = bf16(a), high16 = bf16(b)
__device__ __forceinline__ uint32_t cvtpk_bf16(float a, float b) {
    uint32_t r;
    asm("v_cvt_pk_bf16_f32 %0, %1, %2" : "=v"(r) : "v"(a), "v"(b));
    return r;
}

__device__ __forceinline__ f32x16 mfma32(bf16x8 a, bf16x8 b, f32x16 c) {
    return __builtin_amdgcn_mfma_f32_32x32x16_bf16(a, b, c, 0, 0, 0);
}
__device__ __forceinline__ f32x4 mfma16(bf16x8 a, bf16x8 b, f32x4 c) {
    return __builtin_amdgcn_mfma_f32_16x16x32_bf16(a, b, c, 0, 0, 0);
}

__device__ __forceinline__ float fast_tanh(float x) {
    float e = __expf(2.0f * x);
    return 1.0f - __fdividef(2.0f, e + 1.0f);   // inf-safe
}

// ---------- full 13-channel tanh jet (verified, fallback path) ----------
__device__ __forceinline__ void tanh_jet(float u[13]) {
    float s    = fast_tanh(u[0]);
    float sp   = 1.f - s * s;
    float spp  = -2.f * s * sp;
    float sppp = -2.f * (sp * sp + s * spp);
    float u1 = u[1], u2 = u[2], u3 = u[3];
    float u4 = u[4], u5 = u[5], u6 = u[6];
    u[0] = s;
    u[1] = sp * u1;
    u[2] = sp * u2;
    u[3] = sp * u3;
    u[9]  = sppp * u1 * u1 * u1 + 3.f * spp * u1 * u4 + sp * u[9];
    u[10] = sppp * u1 * u1 * u2 + spp * (u4 * u2 + 2.f * u5 * u1) + sp * u[10];
    u[11] = sppp * u1 * u2 * u2 + spp * (u6 * u1 + 2.f * u5 * u2) + sp * u[11];
    u[12] = sppp * u2 * u2 * u2 + 3.f * spp * u2 * u6 + sp * u[12];
    u[4] = spp * u1 * u1 + sp * u4;
    u[5] = spp * u1 * u2 + sp * u5;
    u[6] = spp * u2 * u2 + sp * u6;
    u[7] = spp * u1 * u3 + sp * u[7];
    u[8] = spp * u2 * u3 + sp * u[8];
}

// ---------- reduced 6-channel jet: 0:val 1:dx 2:dy 3:dt 4:dxt 5:dyt ----------
__device__ __forceinline__ void tanh_jet6(float u[6]) {
    float s   = fast_tanh(u[0]);
    float sp  = 1.f - s * s;
    float spp = -2.f * s * sp;
    float u1 = u[1], u2 = u[2], u3 = u[3];
    u[0] = s;
    u[4] = spp * u1 * u3 + sp * u[4];
    u[5] = spp * u2 * u3 + sp * u[5];
    u[1] = sp * u1;
    u[2] = sp * u2;
    u[3] = sp * u3;
}

// ---------- prep A: 32x32 B-frag order (fallback format, verified) ----------
__global__ __launch_bounds__(256)
void pack_w_kernel(PrepArgs a) {
    bool z = (a.l1[0] == 0.f && a.l2[0] == 0.f);
    if (z != (bool)a.run_on_zero) return;
    int idx = blockIdx.x * 256 + threadIdx.x;   // 7*16*128 = 14336
    int L  = idx >> 11;
    int kb = (idx >> 7) & 15;
    int n  = idx & 127;
    const float* w = a.W[L] + n * 128 + kb * 8;
    float4 f0 = *(const float4*)w;
    float4 f1 = *(const float4*)(w + 4);
    uint32_t h0, h1, h2, h3, l0, l1, l2, l3;
    packPair(f0.x, f0.y, h0, l0);
    packPair(f0.z, f0.w, h1, l1);
    packPair(f1.x, f1.y, h2, l2);
    packPair(f1.z, f1.w, h3, l3);
    a.dst[((L * 2 + 0) * 16 + kb) * 128 + n] = u32x4{h0, h1, h2, h3};
    a.dst[((L * 2 + 1) * 16 + kb) * 128 + n] = u32x4{l0, l1, l2, l3};
}

// ---------- prep B: 16x16 B-frag order (reduced path, R10/R11-verified) ----------
// dst[((L*2+h)*16 + s*4+g)*128 + n] = u32x4 of bf16 pairs W[n][32s+8g+0..7]
__global__ __launch_bounds__(256)
void pack_w16_kernel(PrepArgs a) {
    bool z = (a.l1[0] == 0.f && a.l2[0] == 0.f);
    if (z != (bool)a.run_on_zero) return;
    int idx = blockIdx.x * 256 + threadIdx.x;   // 7*4*4*128 = 14336
    int L = idx >> 11;
    int s = (idx >> 9) & 3;
    int g = (idx >> 7) & 3;
    int n = idx & 127;
    const float* w = a.W[L] + n * 128 + s * 32 + g * 8;
    float4 f0 = *(const float4*)w;
    float4 f1 = *(const float4*)(w + 4);
    uint32_t h0, h1, h2, h3, l0, l1, l2, l3;
    packPair(f0.x, f0.y, h0, l0);
    packPair(f0.z, f0.w, h1, l1);
    packPair(f1.x, f1.y, h2, l2);
    packPair(f1.z, f1.w, h3, l3);
    a.dst[((L * 2 + 0) * 16 + s * 4 + g) * 128 + n] = u32x4{h0, h1, h2, h3};
    a.dst[((L * 2 + 1) * 16 + s * 4 + g) * 128 + n] = u32x4{l0, l1, l2, l3};
}

// ================= reduced path: lambda1 == lambda2 == 0 =================
// R11-verified geometry (82.8 us). 8 points/block, M=48 rows = exactly 3
// 16-row MFMA tiles, zero pad.
// Row map: row(c,p) = 16*(c>>1) + 4*(p>>1) + (c&1) + 2*(p&1).
// 16x16x32 MFMA, C: col=lane&15, row=(lane>>4)*4+reg [m89-verified] =>
// lane (l15,g) holds, for neurons n0=wid*32+l15 and n0+16, the complete
// 6-channel jets of points p=2g+e at static acc indices.
// A: two bf16 planes [48][128], 16B-granule XOR swizzle (verified):
//   addr(row,k) = row*128 + (((k>>3) ^ (row&15))<<3) + (k&7)
__global__ __launch_bounds__(256, 4)   // (256,6) caused spills: VGPR 40, 53MB scratch writes
void pinn_red8_kernel(Args args)
{
    if (args.l1[0] != 0.f || args.l2[0] != 0.f) return;   // uniform guard

    __shared__ ushort Ahi[48 * 128];        // 12 KB
    __shared__ ushort Alo[48 * 128];        // 12 KB
    __shared__ float  Part[4][4][2][9];     // 1.125 KB [wid][g][e][v]

    const int tid   = threadIdx.x;
    const int lane  = tid & 63;
    const int wid   = tid >> 6;
    const int l15   = lane & 15;
    const int g     = lane >> 4;            // 0..3
    const int n0    = wid * 32 + l15;       // ct=0 neuron; ct=1 -> +16
    const int pbase = blockIdx.x * 8;

    auto put_pair = [&](float dA, float dB, int rowA, int n) {
        const int rowB = rowA + 1;
        const int aA = rowA * 128 + ((((n >> 3) ^ (rowA & 15)) << 3) | (n & 7));
        const int aB = rowB * 128 + ((((n >> 3) ^ (rowB & 15)) << 3) | (n & 7));
        uint32_t hp = cvtpk_bf16(dA, dB);
        float hA = __uint_as_float(hp << 16);
        float hB = __uint_as_float(hp & 0xFFFF0000u);
        uint32_t lp = cvtpk_bf16(dA - hA, dB - hB);
        Ahi[aA] = (ushort)hp;  Ahi[aB] = (ushort)(hp >> 16);
        Alo[aA] = (ushort)lp;  Alo[aB] = (ushort)(lp >> 16);
    };
    // store jet of (neuron n, point p=2g+e): channel pairs at rows 16cp+4g+2e, +1
    auto store_jet6 = [&](const float d[6], int e, int n) {
        #pragma unroll
        for (int cp = 0; cp < 3; ++cp) {
            const int rowA = 16 * cp + 4 * g + 2 * e;
            put_pair(d[2 * cp], d[2 * cp + 1], rowA, n);
        }
    };

    // ---- layer 0: closed-form 6-jets; lane: 2 neurons x 2 points ----
    #pragma unroll
    for (int ct = 0; ct < 2; ++ct) {
        const int n = n0 + 16 * ct;
        float w0 = args.W0[n * 3], w1 = args.W0[n * 3 + 1], w2 = args.W0[n * 3 + 2];
        float bb = args.b0[n];
        #pragma unroll
        for (int e = 0; e < 2; ++e) {
            const int p = 2 * g + e;
            float x = args.xs[pbase + p], y = args.ys[pbase + p], tt = args.ts[pbase + p];
            float d[6];
            d[0] = w0 * x + w1 * y + w2 * tt + bb;
            d[1] = w0; d[2] = w1; d[3] = w2;
            d[4] = 0.f; d[5] = 0.f;
            tanh_jet6(d);
            store_jet6(d, e, n);
        }
    }
    __syncthreads();

    for (int L = 1; L <= 7; ++L) {
        const u32x4* whi = args.wpk16 + (size_t)(L - 1) * 4096;
        const u32x4* wlo = whi + 2048;
        f32x4 acc00{}, acc01{}, acc02{};   // ct=0, rt=0..2
        f32x4 acc10{}, acc11{}, acc12{};   // ct=1

        #pragma unroll
        for (int s = 0; s < 4; ++s) {
            const int gb = s * 4 + g;               // k-granule 0..15
            const u32x4 rbh0 = whi[gb * 128 + n0];
            const u32x4 rbh1 = whi[gb * 128 + n0 + 16];
            const u32x4 rbl0 = wlo[gb * 128 + n0];
            const u32x4 rbl1 = wlo[gb * 128 + n0 + 16];

            const int koff = (gb ^ l15) << 3;
            bf16x8 ah0 = __builtin_bit_cast(bf16x8, *(const u32x4*)&Ahi[(     l15) * 128 + koff]);
            bf16x8 ah1 = __builtin_bit_cast(bf16x8, *(const u32x4*)&Ahi[(16 + l15) * 128 + koff]);
            bf16x8 ah2 = __builtin_bit_cast(bf16x8, *(const u32x4*)&Ahi[(32 + l15) * 128 + koff]);
            bf16x8 al0 = __builtin_bit_cast(bf16x8, *(const u32x4*)&Alo[(     l15) * 128 + koff]);
            bf16x8 al1 = __builtin_bit_cast(bf16x8, *(const u32x4*)&Alo[(16 + l15) * 128 + koff]);
            bf16x8 al2 = __builtin_bit_cast(bf16x8, *(const u32x4*)&Alo[(32 + l15) * 128 + koff]);
            bf16x8 bh0 = __builtin_bit_cast(bf16x8, rbh0);
            bf16x8 bh1 = __builtin_bit_cast(bf16x8, rbh1);
            bf16x8 bl0 = __builtin_bit_cast(bf16x8, rbl0);
            bf16x8 bl1 = __builtin_bit_cast(bf16x8, rbl1);

            acc00 = mfma16(ah0, bh0, acc00);
            acc01 = mfma16(ah1, bh0, acc01);
            acc02 = mfma16(ah2, bh0, acc02);
            acc10 = mfma16(ah0, bh1, acc10);
            acc11 = mfma16(ah1, bh1, acc11);
            acc12 = mfma16(ah2, bh1, acc12);
            acc00 = mfma16(al0, bh0, acc00);
            acc01 = mfma16(al1, bh0, acc01);
            acc02 = mfma16(al2, bh0, acc02);
            acc10 = mfma16(al0, bh1, acc10);
            acc11 = mfma16(al1, bh1, acc11);
            acc12 = mfma16(al2, bh1, acc12);
            acc00 = mfma16(ah0, bl0, acc00);
            acc01 = mfma16(ah1, bl0, acc01);
            acc02 = mfma16(ah2, bl0, acc02);
            acc10 = mfma16(ah0, bl1, acc10);
            acc11 = mfma16(ah1, bl1, acc11);
            acc12 = mfma16(ah2, bl1, acc12);
        }

        __syncthreads();   // all waves finished reading A

        if (L < 7) {
            #pragma unroll
            for (int ct = 0; ct < 2; ++ct) {
                const int n = n0 + 16 * ct;
                const float bL = args.bias[L][n];
                #pragma unroll
                for (int e = 0; e < 2; ++e) {
                    float d[6];
                    if (ct == 0) {
                        d[0] = acc00[2 * e]; d[1] = acc00[1 + 2 * e];
                        d[2] = acc01[2 * e]; d[3] = acc01[1 + 2 * e];
                        d[4] = acc02[2 * e]; d[5] = acc02[1 + 2 * e];
                    } else {
                        d[0] = acc10[2 * e]; d[1] = acc10[1 + 2 * e];
                        d[2] = acc11[2 * e]; d[3] = acc11[1 + 2 * e];
                        d[4] = acc12[2 * e]; d[5] = acc12[1 + 2 * e];
                    }
                    d[0] += bL;
                    tanh_jet6(d);
                    store_jet6(d, e, n);
                }
            }
            __syncthreads();   // A ready for next layer
        } else {
            #pragma unroll
            for (int e = 0; e < 2; ++e) {
                float rp[9];
                #pragma unroll
                for (int v = 0; v < 9; ++v) rp[v] = 0.f;
                #pragma unroll
                for (int ct = 0; ct < 2; ++ct) {
                    const int n = n0 + 16 * ct;
                    const float bL = args.bias[7][n];
                    const float wp = args.W8[n], wq = args.W8[128 + n];
                    float d[6];
                    if (ct == 0) {
                        d[0] = acc00[2 * e]; d[1] = acc00[1 + 2 * e];
                        d[2] = acc01[2 * e]; d[3] = acc01[1 + 2 * e];
                        d[4] = acc02[2 * e]; d[5] = acc02[1 + 2 * e];
                    } else {
                        d[0] = acc10[2 * e]; d[1] = acc10[1 + 2 * e];
                        d[2] = acc11[2 * e]; d[3] = acc11[1 + 2 * e];
                        d[4] = acc12[2 * e]; d[5] = acc12[1 + 2 * e];
                    }
                    d[0] += bL;
                    tanh_jet6(d);
                    #pragma unroll
                    for (int c = 0; c < 6; ++c) rp[c] += wp * d[c];
                    rp[6] += wq * d[0]; rp[7] += wq * d[1]; rp[8] += wq * d[2];
                }
                #pragma unroll
                for (int v = 0; v < 9; ++v) {
                    float sv = rp[v];
                    sv += __shfl_xor(sv, 8); sv += __shfl_xor(sv, 4);
                    sv += __shfl_xor(sv, 2); sv += __shfl_xor(sv, 1);
                    rp[v] = sv;
                }
                if (l15 == 0) {
                    #pragma unroll
                    for (int v = 0; v < 9; ++v) Part[wid][g][e][v] = rp[v];
                }
            }
        }
    }

    __syncthreads();   // Part visible

    if (tid < 8) {
        const int p = tid, gg = p >> 1, e = p & 1;
        float s[9];
        #pragma unroll
        for (int v = 0; v < 9; ++v)
            s[v] = Part[0][gg][e][v] + Part[1][gg][e][v]
                 + Part[2][gg][e][v] + Part[3][gg][e][v];

        float u   = s[2];              // psi_y
        float v   = -s[1];             // -psi_x
        float pv  = s[6] + args.b8[1]; // p
        float f_u = s[5] + s[7];       // psi_yt + p_x      (lambda = 0)
        float f_v = -s[4] + s[8];      // -psi_xt + p_y
        const int pt = pbase + p;
        float* out = args.out;
        out[0 * NPTS + pt] = u;
        out[1 * NPTS + pt] = v;
        out[2 * NPTS + pt] = pv;
        out[3 * NPTS + pt] = f_u;
        out[4 * NPTS + pt] = f_v;
    }
}

// ================= full path (R7-verified), runs only when lambda != 0 =========
__global__ __launch_bounds__(256, 2)
void pinn_mfma6_kernel(Args args)
{
    if (args.l1[0] == 0.f && args.l2[0] == 0.f) return;   // reduced path handles it

    __shared__ ushort Ahi[128 * 128];       // 32 KB
    __shared__ ushort Alo[128 * 128];       // 32 KB
    __shared__ float  Part[4][2][4][16];    // 2 KB

    const int tid   = threadIdx.x;
    const int lane  = tid & 63;
    const int wid   = tid >> 6;
    const int ln31  = lane & 31;
    const int kh    = lane >> 5;
    const int n     = wid * 32 + ln31;
    const int pbase = blockIdx.x * 8;

    auto store_jet = [&](const float d[13], int j) {
        const int rb = 32 * j + 4 * kh;
        #pragma unroll
        for (int cp = 0; cp < 6; ++cp) {
            const int cA = 2 * cp, cB = cA + 1;
            const int rowA = rb + 8 * (cA >> 2) + (cA & 3);
            const int rowB = rb + 8 * (cB >> 2) + (cB & 3);
            const int aA = rowA * 128 + ((((n >> 3) ^ (rowA & 15)) << 3) | (n & 7));
            const int aB = rowB * 128 + ((((n >> 3) ^ (rowB & 15)) << 3) | (n & 7));
            uint32_t hp = cvtpk_bf16(d[cA], d[cB]);
            float hA = __uint_as_float(hp << 16);
            float hB = __uint_as_float(hp & 0xFFFF0000u);
            uint32_t lp = cvtpk_bf16(d[cA] - hA, d[cB] - hB);
            Ahi[aA] = (ushort)hp; Ahi[aB] = (ushort)(hp >> 16);
            Alo[aA] = (ushort)lp; Alo[aB] = (ushort)(lp >> 16);
        }
        {
            const int row = rb + 24;
            const int a12 = row * 128 + ((((n >> 3) ^ (row & 15)) << 3) | (n & 7));
            uint32_t hp = cvtpk_bf16(d[12], 0.f);
            float h = __uint_as_float(hp << 16);
            uint32_t lp = cvtpk_bf16(d[12] - h, 0.f);
            Ahi[a12] = (ushort)hp;
            Alo[a12] = (ushort)lp;
        }
    };

    {
        float w0 = args.W0[n * 3], w1 = args.W0[n * 3 + 1], w2 = args.W0[n * 3 + 2];
        float bb = args.b0[n];
        #pragma unroll
        for (int j = 0; j < 4; ++j) {
            const int p = j + 4 * kh;
            float x = args.xs[pbase + p], y = args.ys[pbase + p], t = args.ts[pbase + p];
            float d[13];
            #pragma unroll
            for (int c = 4; c < 13; ++c) d[c] = 0.f;
            d[0] = w0 * x + w1 * y + w2 * t + bb;
            d[1] = w0; d[2] = w1; d[3] = w2;
            tanh_jet(d);
            store_jet(d, j);
        }
        #pragma unroll
        for (int i = 0; i < 12; ++i) {
            int idx  = tid + 256 * i;
            int pl   = (idx >= 1536) ? 1 : 0;
            int rem  = idx - 1536 * pl;
            int rowi = rem >> 6;
            int w    = rem & 63;
            int t4   = rowi / 6, s = rowi - 6 * t4;
            int row  = 32 * t4 + 24 + 4 * (s / 3) + 1 + (s % 3);
            uint32_t* P = pl ? (uint32_t*)Alo : (uint32_t*)Ahi;
            P[row * 64 + w] = 0;
        }
    }
    __syncthreads();

    for (int L = 1; L <= 7; ++L) {
        const u32x4* whi = args.wpk + (size_t)(L - 1) * 4096;
        const u32x4* wlo = whi + 2048;
        f32x16 acc0{}, acc1{}, acc2{}, acc3{};

        #pragma unroll
        for (int ks = 0; ks < 8; ++ks) {
            const int kb = ks * 2 + kh;
            const u32x4 rbh = whi[kb * 128 + n];
            const u32x4 rbl = wlo[kb * 128 + n];

            const int koff = (kb ^ (ln31 & 15)) << 3;
            const int e0 = (ln31      ) * 128 + koff;
            const int e1 = (ln31 + 32 ) * 128 + koff;
            const int e2 = (ln31 + 64 ) * 128 + koff;
            const int e3 = (ln31 + 96 ) * 128 + koff;
            bf16x8 ah0 = __builtin_bit_cast(bf16x8, *(const u32x4*)&Ahi[e0]);
            bf16x8 ah1 = __builtin_bit_cast(bf16x8, *(const u32x4*)&Ahi[e1]);
            bf16x8 ah2 = __builtin_bit_cast(bf16x8, *(const u32x4*)&Ahi[e2]);
            bf16x8 ah3 = __builtin_bit_cast(bf16x8, *(const u32x4*)&Ahi[e3]);
            bf16x8 al0 = __builtin_bit_cast(bf16x8, *(const u32x4*)&Alo[e0]);
            bf16x8 al1 = __builtin_bit_cast(bf16x8, *(const u32x4*)&Alo[e1]);
            bf16x8 al2 = __builtin_bit_cast(bf16x8, *(const u32x4*)&Alo[e2]);
            bf16x8 al3 = __builtin_bit_cast(bf16x8, *(const u32x4*)&Alo[e3]);
            bf16x8 bh  = __builtin_bit_cast(bf16x8, rbh);
            bf16x8 bl  = __builtin_bit_cast(bf16x8, rbl);

            acc0 = mfma32(ah0, bh, acc0);
            acc1 = mfma32(ah1, bh, acc1);
            acc2 = mfma32(ah2, bh, acc2);
            acc3 = mfma32(ah3, bh, acc3);
            acc0 = mfma32(al0, bh, acc0);
            acc1 = mfma32(al1, bh, acc1);
            acc2 = mfma32(al2, bh, acc2);
            acc3 = mfma32(al3, bh, acc3);
            acc0 = mfma32(ah0, bl, acc0);
            acc1 = mfma32(ah1, bl, acc1);
            acc2 = mfma32(ah2, bl, acc2);
            acc3 = mfma32(ah3, bl, acc3);
        }

        __syncthreads();

        const float bL = args.bias[L][n];

        if (L < 7) {
            #pragma unroll
            for (int j = 0; j < 4; ++j) {
                float d[13];
                #pragma unroll
                for (int c = 0; c < 13; ++c)
                    d[c] = (j == 0) ? acc0[c] : (j == 1) ? acc1[c] : (j == 2) ? acc2[c] : acc3[c];
                d[0] += bL;
                tanh_jet(d);
                store_jet(d, j);
            }
            __syncthreads();
        } else {
            const float wp = args.W8[n], wq = args.W8[128 + n];
            #pragma unroll
            for (int j = 0; j < 4; ++j) {
                float d[13];
                #pragma unroll
                for (int c = 0; c < 13; ++c)
                    d[c] = (j == 0) ? acc0[c] : (j == 1) ? acc1[c] : (j == 2) ? acc2[c] : acc3[c];
                d[0] += bL;
                tanh_jet(d);
                float rp[16];
                #pragma unroll
                for (int c = 0; c < 13; ++c) rp[c] = wp * d[c];
                rp[13] = wq * d[0]; rp[14] = wq * d[1]; rp[15] = wq * d[2];
                #pragma unroll
                for (int v = 0; v < 16; ++v) {
                    float s = rp[v];
                    s += __shfl_xor(s, 16); s += __shfl_xor(s, 8);
                    s += __shfl_xor(s, 4);  s += __shfl_xor(s, 2);
                    s += __shfl_xor(s, 1);
                    rp[v] = s;
                }
                if (ln31 == 0) {
                    #pragma unroll
                    for (int v = 0; v < 16; ++v) Part[wid][kh][j][v] = rp[v];
                }
            }
        }
    }

    __syncthreads();

    if (tid < 8) {
        const int p = tid, khp = p >> 2, jp = p & 3;
        float s[16];
        #pragma unroll
        for (int v = 0; v < 16; ++v)
            s[v] = Part[0][khp][jp][v] + Part[1][khp][jp][v]
                 + Part[2][khp][jp][v] + Part[3][khp][jp][v];

        float l1 = args.l1[0], l2 = args.l2[0];
        float u    = s[2];
        float v    = -s[1];
        float pv   = s[13] + args.b8[1];
        float u_t  = s[8];
        float v_t  = -s[7];
        float u_x  = s[5];
        float u_y  = s[6];
        float v_x  = -s[4];
        float v_y  = -s[5];
        float u_xx = s[10];
        float u_yy = s[12];
        float v_xx = -s[9];
        float v_yy = -s[11];
        float p_x = s[14], p_y = s[15];
        float f_u = u_t + l1 * (u * u_x + v * u_y) + p_x - l2 * (u_xx + u_yy);
        float f_v = v_t + l1 * (u * v_x + v * v_y) + p_y - l2 * (v_xx + v_yy);
        const int pt = pbase + p;
        float* out = args.out;
        out[0 * NPTS + pt] = u;
        out[1 * NPTS + pt] = v;
        out[2 * NPTS + pt] = pv;
        out[3 * NPTS + pt] = f_u;
        out[4 * NPTS + pt] = f_v;
    }
}

extern "C" void kernel_launch(void* const* d_in, const int* in_sizes, int n_in,
                              void* d_out, int out_size, void* d_ws, size_t ws_size,
                              hipStream_t stream) {
    const float* l1p = (const float*)d_in[21];
    const float* l2p = (const float*)d_in[22];

    // 16x16 format at d_ws (448 KB), 32x32 format at d_ws+448KB
    u32x4* wpk16 = (u32x4*)d_ws;
    u32x4* wpkOld = (u32x4*)((char*)d_ws + 448 * 1024);

    PrepArgs pa16;
    for (int i = 0; i < 7; ++i) pa16.W[i] = (const float*)d_in[2 * (i + 1)];
    pa16.dst = wpk16; pa16.l1 = l1p; pa16.l2 = l2p; pa16.run_on_zero = 1;
    pack_w16_kernel<<<56, 256, 0, stream>>>(pa16);

    PrepArgs paOld = pa16;
    paOld.dst = wpkOld; paOld.run_on_zero = 0;
    pack_w_kernel<<<56, 256, 0, stream>>>(paOld);

    Args a;
    a.W0 = (const float*)d_in[0];
    a.b0 = (const float*)d_in[1];
    a.bias[0] = nullptr;
    for (int L = 1; L <= 7; ++L) a.bias[L] = (const float*)d_in[2 * L + 1];
    a.W8 = (const float*)d_in[16];
    a.b8 = (const float*)d_in[17];
    a.xs = (const float*)d_in[18];
    a.ys = (const float*)d_in[19];
    a.ts = (const float*)d_in[20];
    a.l1 = l1p;
    a.l2 = l2p;
    a.wpk = wpkOld;
    a.wpk16 = wpk16;
    a.out = (float*)d_out;

    pinn_red8_kernel<<<NPTS / 8, 256, 0, stream>>>(a);    // runs iff lambda == 0
    pinn_mfma6_kernel<<<NPTS / 8, 256, 0, stream>>>(a);   // runs iff lambda != 0
}